// Round 9
// baseline (191.109 us; speedup 1.0000x reference)
//
#include <hip/hip_runtime.h>
#include <hip/hip_bf16.h>

// Problem constants
#define BATCH 2
#define SLEN  2048
#define DM    1024
#define NH    16
#define NKH   4
#define HD    64
#define NCH   4          // flash K-split: 4 chunks of 512 keys
#define PSTRIDE (BATCH * SLEN * NH * HD)   // 4,194,304 floats per chunk
#define LSTRIDE (BATCH * SLEN * NH)        // 65,536 floats per chunk

typedef __attribute__((ext_vector_type(8))) short short8;   // 8 bf16 (MFMA A/B frag)
typedef __attribute__((ext_vector_type(4))) float f32x4;    // MFMA C/D frag

// fp32 -> bf16 (RNE) as raw bits
static __device__ __forceinline__ short f2bf(float x) {
    unsigned u = __float_as_uint(x);
    u += 0x7fffu + ((u >> 16) & 1u);
    return (short)(u >> 16);
}

// async global->LDS, 16 bytes per lane. LDS dest must be uniform base + lane*16.
static __device__ __forceinline__ void ldg_lds16(const short* g, short* l) {
    __builtin_amdgcn_global_load_lds(
        (const __attribute__((address_space(1))) unsigned int*)(const void*)g,
        (__attribute__((address_space(3))) unsigned int*)(void*)l,
        16, 0, 0);
}

// log2(e)/8 : folds the 1/sqrt(HD) score scale and exp->exp2 into Q proj.
#define QSCALE 0.1803368801f

// ---------------------------------------------------------------------------
// Fused preprocessing: weight transposes (by < 40) + x fp32->bf16 (by >= 40).
// W fp32 [1024(K)][Nc] -> T bf16 rows (rowoff+n)[1024].
// ---------------------------------------------------------------------------
__global__ __launch_bounds__(256) void prep_all(
    const float* __restrict__ wq, const float* __restrict__ wk,
    const float* __restrict__ wv, const float* __restrict__ wo,
    short* __restrict__ T,
    const float* __restrict__ X, short* __restrict__ Xb)
{
    const int by = blockIdx.y;
    const int t  = threadIdx.x;

    if (by >= 40) {
        // x -> bf16: 128 blocks x 256 threads x 16 float8 groups
        const int blk = (by - 40) * 16 + blockIdx.x;    // 0..127
#pragma unroll
        for (int j = 0; j < 16; ++j) {
            const int i = blk * 4096 + j * 256 + t;
            const float4 v0 = ((const float4*)X)[i * 2];
            const float4 v1 = ((const float4*)X)[i * 2 + 1];
            __align__(16) short o[8];
            o[0] = f2bf(v0.x); o[1] = f2bf(v0.y); o[2] = f2bf(v0.z); o[3] = f2bf(v0.w);
            o[4] = f2bf(v1.x); o[5] = f2bf(v1.y); o[6] = f2bf(v1.z); o[7] = f2bf(v1.w);
            ((int4*)Xb)[i] = *(const int4*)o;
        }
        return;
    }

    const float* W; int Nc, rowoff, ntile;
    if (by < 16)      { W = wq; Nc = 1024; rowoff = 0;    ntile = by; }
    else if (by < 20) { W = wk; Nc = 256;  rowoff = 1024; ntile = by - 16; }
    else if (by < 24) { W = wv; Nc = 256;  rowoff = 1280; ntile = by - 20; }
    else              { W = wo; Nc = 1024; rowoff = 1536; ntile = by - 24; }
    const int kt = blockIdx.x * 64;
    const int nt = ntile * 64;
    __shared__ float tile[64][65];

#pragma unroll
    for (int i = 0; i < 4; ++i) {
        const int r = (t >> 4) + i * 16;
        const int c = (t & 15) * 4;
        const float4 v = *(const float4*)(W + (size_t)(kt + r) * Nc + nt + c);
        tile[r][c + 0] = v.x; tile[r][c + 1] = v.y;
        tile[r][c + 2] = v.z; tile[r][c + 3] = v.w;
    }
    __syncthreads();
#pragma unroll
    for (int i = 0; i < 2; ++i) {
        const int rr = (t >> 3) + i * 32;
        const int cc = (t & 7) * 8;
        __align__(16) short o[8];
#pragma unroll
        for (int j = 0; j < 8; ++j) o[j] = f2bf(tile[cc + j][rr]);
        *(int4*)(T + (size_t)(rowoff + nt + rr) * 1024 + kt + cc) = *(const int4*)o;
    }
}

// ---------------------------------------------------------------------------
// bf16 MFMA GEMM: C[M,N] = A[M,K] * Bt[N,K]^T.  64x128 tile (M x N), BK=64,
// 256 threads (4 waves in 2x2, wave tile 32x64), global_load_lds staging.
// MODE 0: fused QKV epilogue (RoPE, QSCALE, V natural layout).
// MODE 1: plain fp32 C output.
// ---------------------------------------------------------------------------
template<int MODE>
__global__ __launch_bounds__(256) void gemm_abt(
    const short* __restrict__ A, const short* __restrict__ Bt,
    int M, int N, int K,
    float* __restrict__ Cf,
    short* __restrict__ Qb, short* __restrict__ Kb, short* __restrict__ Vb,
    const float* __restrict__ cosp, const float* __restrict__ sinp)
{
    const int t    = threadIdx.x;
    const int lane = t & 63;
    const int w    = t >> 6;
    const int l15  = lane & 15;
    const int l4   = lane >> 4;
    const int n0   = blockIdx.x * 128;
    const int m0   = blockIdx.y * 64;
    const int wm   = (w & 1) * 32;
    const int wn   = (w >> 1) * 64;

    __shared__ __align__(16) short As[64 * 64];    // 8 KB
    __shared__ __align__(16) short Bs[128 * 64];   // 16 KB

    f32x4 acc[2][4];
#pragma unroll
    for (int i = 0; i < 2; ++i)
#pragma unroll
        for (int j = 0; j < 4; ++j) acc[i][j] = (f32x4){0.f, 0.f, 0.f, 0.f};

    for (int kt = 0; kt < K; kt += 64) {
        __syncthreads();
#pragma unroll
        for (int i = 0; i < 2; ++i) {              // A: 512 chunks
            const int chunk = i * 256 + t;
            const int r = chunk >> 3;
            const int c = (chunk & 7) * 8;
            ldg_lds16(A + (size_t)(m0 + r) * K + kt + c, &As[chunk * 8]);
        }
#pragma unroll
        for (int i = 0; i < 4; ++i) {              // B: 1024 chunks
            const int chunk = i * 256 + t;
            const int r = chunk >> 3;
            const int c = (chunk & 7) * 8;
            ldg_lds16(Bt + (size_t)(n0 + r) * K + kt + c, &Bs[chunk * 8]);
        }
        __syncthreads();

#pragma unroll
        for (int k2 = 0; k2 < 2; ++k2) {
            short8 af[2], bf[4];
#pragma unroll
            for (int i = 0; i < 2; ++i)
                af[i] = *(const short8*)&As[(wm + i * 16 + l15) * 64 + k2 * 32 + l4 * 8];
#pragma unroll
            for (int j = 0; j < 4; ++j)
                bf[j] = *(const short8*)&Bs[(wn + j * 16 + l15) * 64 + k2 * 32 + l4 * 8];
#pragma unroll
            for (int i = 0; i < 2; ++i)
#pragma unroll
                for (int j = 0; j < 4; ++j)
                    acc[i][j] = __builtin_amdgcn_mfma_f32_16x16x32_bf16(af[i], bf[j], acc[i][j], 0, 0, 0);
        }
    }

    if (MODE == 1) {
#pragma unroll
        for (int i = 0; i < 2; ++i)
#pragma unroll
            for (int j = 0; j < 4; ++j)
#pragma unroll
                for (int r = 0; r < 4; ++r) {
                    const int m = m0 + wm + i * 16 + l4 * 4 + r;
                    const int n = n0 + wn + j * 16 + l15;
                    Cf[(size_t)m * N + n] = acc[i][j][r];
                }
        return;
    }

    // MODE 0: fused QKV epilogue. This wave's 64-col span = exactly one head.
    const int colbase = n0 + wn;
    if (colbase < 1024) {
        const int h = colbase >> 6;              // Q head (exp2-domain scale)
#pragma unroll
        for (int i = 0; i < 2; ++i)
#pragma unroll
            for (int r = 0; r < 4; ++r) {
                const int m = m0 + wm + i * 16 + l4 * 4 + r;
                const int b = m >> 11, s = m & (SLEN - 1);
                short* dst = Qb + (((size_t)(b * SLEN + s) * NH + h) << 6);
#pragma unroll
                for (int j = 0; j < 2; ++j) {
                    const int d = j * 16 + l15;
                    const float cv = cosp[s * HD + d];
                    const float sv = sinp[s * HD + d];
                    const float a0 = acc[i][j][r];
                    const float a1 = acc[i][j + 2][r];
                    dst[d]      = f2bf((a0 * cv - a1 * sv) * QSCALE);
                    dst[d + 32] = f2bf((a1 * cv + a0 * sv) * QSCALE);
                }
            }
    } else if (colbase < 1280) {
        const int kh = (colbase - 1024) >> 6;    // K head
#pragma unroll
        for (int i = 0; i < 2; ++i)
#pragma unroll
            for (int r = 0; r < 4; ++r) {
                const int m = m0 + wm + i * 16 + l4 * 4 + r;
                const int b = m >> 11, s = m & (SLEN - 1);
                short* dst = Kb + (((size_t)(b * SLEN + s) * NKH + kh) << 6);
#pragma unroll
                for (int j = 0; j < 2; ++j) {
                    const int d = j * 16 + l15;
                    const float cv = cosp[s * HD + d];
                    const float sv = sinp[s * HD + d];
                    const float a0 = acc[i][j][r];
                    const float a1 = acc[i][j + 2][r];
                    dst[d]      = f2bf(a0 * cv - a1 * sv);
                    dst[d + 32] = f2bf(a1 * cv + a0 * sv);
                }
            }
    } else {
        const int kh = (colbase - 1280) >> 6;    // V head -> natural layout
#pragma unroll
        for (int i = 0; i < 2; ++i)
#pragma unroll
            for (int r = 0; r < 4; ++r) {
                const int m = m0 + wm + i * 16 + l4 * 4 + r;
                const int b = m >> 11, s = m & (SLEN - 1);
                short* dst = Vb + (((size_t)(b * SLEN + s) * NKH + kh) << 6);
#pragma unroll
                for (int j = 0; j < 4; ++j)
                    dst[j * 16 + l15] = f2bf(acc[i][j][r]);
            }
    }
}

// ---------------------------------------------------------------------------
// V transpose: Vb bf16 [B,S,KH,64] -> Vt bf16 [B,KH,64(d),S], with the
// per-64-tile key permutation sp = 4*(u&15) + (u>>4) baked in.
// ---------------------------------------------------------------------------
__global__ __launch_bounds__(256) void vtrans_b(
    const short* __restrict__ Vb, short* __restrict__ Vt)
{
    const int s0 = blockIdx.x * 64;
    const int kh = blockIdx.y;
    const int b  = blockIdx.z;
    const int t  = threadIdx.x;
    __shared__ short tile[64][72];

#pragma unroll
    for (int i = 0; i < 2; ++i) {
        const int chunk = i * 256 + t;
        const int r = chunk >> 3;            // s row 0..63
        const int c = (chunk & 7) * 8;       // d col
        *(int4*)&tile[r][c] =
            *(const int4*)(Vb + (((size_t)(b * SLEN + s0 + r) * NKH + kh) << 6) + c);
    }
    __syncthreads();
#pragma unroll
    for (int i = 0; i < 2; ++i) {
        const int chunk = i * 256 + t;
        const int d  = chunk >> 3;           // 0..63
        const int sc = (chunk & 7) * 8;      // sp chunk base
        __align__(16) short o[8];
#pragma unroll
        for (int j = 0; j < 8; ++j) {
            const int sp = sc + j;
            const int u  = ((sp & 3) << 4) | (sp >> 2);   // inverse permutation
            o[j] = tile[u][d];
        }
        *(int4*)(Vt + ((size_t)((b * NKH + kh) * HD + d)) * SLEN + s0 + sc) = *(const int4*)o;
    }
}

// ---------------------------------------------------------------------------
// Flash attention v7: K-split + dbuf (1 barrier/iter) AT 4 BLOCKS/CU.
// LDS budget for 4/CU is 40960 B exactly: Ks/Vs dbuf 32768 (unpadded,
// global_load_lds) + Ps 8192. Ps shrunk 18432->8192 by (a) 16 rows/wave,
// reused for both 16-query halves (same-wave DS ordering), (b) unpadded
// 64-short rows with chunk-XOR swizzle phys_chunk = chunk ^ (row&7)
// (writes 2-way=free; ap reads 8-way but only 4 instrs/iter on an
// unsaturated LDS pipe). R8 lesson: dbuf at 3 blocks/CU was neutral —
// occupancy is the binding constraint, so buy it back.
// ---------------------------------------------------------------------------
__global__ __launch_bounds__(256, 4) void flash_mfma(
    const short* __restrict__ Qb,   // [B,S,NH,64] bf16 (scaled QSCALE)
    const short* __restrict__ Kb,   // [B,S,NKH,64] bf16
    const short* __restrict__ Vt,   // [B,NKH,64,S] bf16, key-permuted per 64
    short* __restrict__ O,          // [B,S,NH,64] bf16 (direct path, s<512)
    float* __restrict__ Op,         // [NCH][B,S,NH,64] fp32 partial O
    float* __restrict__ Lp)         // [NCH][B,S,NH]    fp32 partial l
{
    const int qs = 63 - blockIdx.x;               // heavy strips first
    const int kc = blockIdx.y & 3;
    if (kc * 16 > qs) return;                     // inactive (chunk > diagonal)
    const int kh = blockIdx.y >> 2;
    const int b  = blockIdx.z;
    const int t    = threadIdx.x;
    const int lane = t & 63;
    const int w    = t >> 6;
    const int h    = kh * 4 + w;                  // this wave's Q head
    const int l15  = lane & 15;
    const int l4   = lane >> 4;
    const int q0   = qs * 32;
    const int sw   = l15 & 7;                     // K/V frag-read swizzle key

    __shared__ __align__(16) short Ks[2][64 * 64];   // 16 KB, dbuf
    __shared__ __align__(16) short Vs[2][64 * 64];   // 16 KB, dbuf
    __shared__ __align__(16) short Ps[4][16 * 64];   // 8 KB (16 rows/wave)

    // staging: 512 chunks per tile, source col swizzled
    const int r_st  = t >> 3;                      // 0..31 (+32 for 2nd half)
    const int c8_st = t & 7;

    // Q fragments in registers
    short8 aq[2][2];
#pragma unroll
    for (int i = 0; i < 2; ++i)
#pragma unroll
        for (int ks = 0; ks < 2; ++ks)
            aq[i][ks] = *(const short8*)(
                Qb + ((size_t)((b * SLEN + q0 + i * 16 + l15) * NH + h)) * HD + ks * 32 + l4 * 8);

    f32x4 acc[2][4];
    f32x4 accl[2];
#pragma unroll
    for (int i = 0; i < 2; ++i) {
#pragma unroll
        for (int nt = 0; nt < 4; ++nt) acc[i][nt] = (f32x4){0.f, 0.f, 0.f, 0.f};
        accl[i] = (f32x4){0.f, 0.f, 0.f, 0.f};
    }

    const short8 ones8 = {0x3f80, 0x3f80, 0x3f80, 0x3f80, 0x3f80, 0x3f80, 0x3f80, 0x3f80};

    const int ntiles = (q0 >> 6) + 1;             // global causal tile count
    const int kt0  = kc * 8;
    const int kend = (kt0 + 8 < ntiles) ? kt0 + 8 : ntiles;

#define STAGE(BI, K0)                                                          \
    {                                                                          \
        _Pragma("unroll")                                                      \
        for (int i_ = 0; i_ < 2; ++i_) {                                       \
            const int r  = i_ * 32 + r_st;                                     \
            const int cs = (c8_st ^ (r & 7)) * 8;                              \
            const int ch = i_ * 256 + t;                                       \
            ldg_lds16(Kb + ((size_t)((b * SLEN + (K0) + r) * NKH + kh)) * HD + cs, \
                      &Ks[BI][ch * 8]);                                        \
            ldg_lds16(Vt + ((size_t)((b * NKH + kh) * HD + r)) * SLEN + (K0) + cs, \
                      &Vs[BI][ch * 8]);                                        \
        }                                                                      \
    }

    STAGE(0, kt0 * 64)

    for (int kt = kt0; kt < kend; ++kt) {
        const int bi = (kt - kt0) & 1;
        __syncthreads();   // drains own staging vmcnt; all waves past prev compute
        if (kt + 1 < kend) STAGE(bi ^ 1, (kt + 1) * 64)

        // ---- QK^T: 16 MFMA ----
        f32x4 sf[2][4];
#pragma unroll
        for (int i = 0; i < 2; ++i)
#pragma unroll
            for (int f = 0; f < 4; ++f) sf[i][f] = (f32x4){0.f, 0.f, 0.f, 0.f};
#pragma unroll
        for (int ks = 0; ks < 2; ++ks)
#pragma unroll
            for (int f = 0; f < 4; ++f) {
                const short8 bk = *(const short8*)
                    &Ks[bi][(f * 16 + l15) * 64 + ((ks * 4 + l4) ^ sw) * 8];
#pragma unroll
                for (int i = 0; i < 2; ++i)
                    sf[i][f] = __builtin_amdgcn_mfma_f32_16x16x32_bf16(aq[i][ks], bk, sf[i][f], 0, 0, 0);
            }

        // causal mask (only the globally-last tile can violate)
        if (kt == ntiles - 1) {
            const int k0 = kt * 64;
#pragma unroll
            for (int i = 0; i < 2; ++i)
#pragma unroll
                for (int f = 0; f < 4; ++f)
#pragma unroll
                    for (int r = 0; r < 4; ++r)
                        if (k0 + f * 16 + l15 > q0 + i * 16 + l4 * 4 + r)
                            sf[i][f][r] = -1e30f;
        }

        // ---- per 16-query half: p = exp2(s), write Ps (16 rows, reused),
        //      then PV for that half. Same-wave DS ordering makes the reuse
        //      safe (i=1 writes queue behind i=0's ap reads). ----
#pragma unroll
        for (int i = 0; i < 2; ++i) {
#pragma unroll
            for (int r = 0; r < 4; ++r) {
                __align__(8) short pk[4];
#pragma unroll
                for (int f = 0; f < 4; ++f) pk[f] = f2bf(exp2f(sf[i][f][r]));
                const int row = l4 * 4 + r;
                *(int2*)&Ps[w][row * 64 + (((l15 >> 1) ^ (row & 7)) << 3) + ((l15 & 1) << 2)] =
                    *(const int2*)pk;
            }
#pragma unroll
            for (int ks = 0; ks < 2; ++ks) {
                const short8 ap = *(const short8*)
                    &Ps[w][l15 * 64 + (((ks * 4 + l4) ^ (l15 & 7)) << 3)];
#pragma unroll
                for (int nt = 0; nt < 4; ++nt) {
                    const short8 bv = *(const short8*)
                        &Vs[bi][(nt * 16 + l15) * 64 + ((ks * 4 + l4) ^ sw) * 8];
                    acc[i][nt] = __builtin_amdgcn_mfma_f32_16x16x32_bf16(ap, bv, acc[i][nt], 0, 0, 0);
                }
                accl[i] = __builtin_amdgcn_mfma_f32_16x16x32_bf16(ap, ones8, accl[i], 0, 0, 0);
            }
        }
    }

    if (q0 < 512) {
        // single active chunk: normalized direct write
#pragma unroll
        for (int i = 0; i < 2; ++i) {
            float rl[4];
#pragma unroll
            for (int r = 0; r < 4; ++r) rl[r] = 1.f / accl[i][r];
#pragma unroll
            for (int nt = 0; nt < 4; ++nt)
#pragma unroll
                for (int r = 0; r < 4; ++r) {
                    const int q = q0 + i * 16 + l4 * 4 + r;
                    O[((size_t)((b * SLEN + q) * NH + h)) * HD + nt * 16 + l15] =
                        f2bf(acc[i][nt][r] * rl[r]);
                }
        }
    } else {
        // partial write (combined by addition in combine_k)
        const size_t pbase = (size_t)kc * PSTRIDE;
#pragma unroll
        for (int i = 0; i < 2; ++i)
#pragma unroll
            for (int nt = 0; nt < 4; ++nt)
#pragma unroll
                for (int r = 0; r < 4; ++r) {
                    const int q = q0 + i * 16 + l4 * 4 + r;
                    Op[pbase + ((size_t)((b * SLEN + q) * NH + h)) * HD + nt * 16 + l15] =
                        acc[i][nt][r];
                }
        if (l15 == 0) {
#pragma unroll
            for (int i = 0; i < 2; ++i)
#pragma unroll
                for (int r = 0; r < 4; ++r) {
                    const int q = q0 + i * 16 + l4 * 4 + r;
                    Lp[(size_t)kc * LSTRIDE + (size_t)(b * SLEN + q) * NH + h] = accl[i][r];
                }
        }
    }
}

// ---------------------------------------------------------------------------
// Combine K-split partials for s >= 512: O = (Σ acc_kc) / (Σ l_kc), bf16 out.
// ---------------------------------------------------------------------------
__global__ void combine_k(const float* __restrict__ Op, const float* __restrict__ Lp,
                          short* __restrict__ O)
{
    const int idx = blockIdx.x * 256 + threadIdx.x;   // < B*1536*NH*16
    const int dq = idx & 15;
    const int h  = (idx >> 4) & 15;
    const int rr = idx >> 8;                          // 0..3071
    const int b  = rr / 1536;
    const int s  = 512 + (rr - b * 1536);
    const int nact = (s >> 9) + 1;                    // 2..4 active chunks
    const size_t row = (size_t)(b * SLEN + s) * NH + h;

    float4 o = {0.f, 0.f, 0.f, 0.f};
    float l = 0.f;
    for (int kc = 0; kc < nact; ++kc) {
        const float4 p = *(const float4*)(Op + (size_t)kc * PSTRIDE + row * HD + dq * 4);
        o.x += p.x; o.y += p.y; o.z += p.z; o.w += p.w;
        l += Lp[(size_t)kc * LSTRIDE + row];
    }
    const float rl = 1.f / l;
    __align__(8) short pk[4];
    pk[0] = f2bf(o.x * rl); pk[1] = f2bf(o.y * rl);
    pk[2] = f2bf(o.z * rl); pk[3] = f2bf(o.w * rl);
    *(int2*)(O + row * HD + dq * 4) = *(const int2*)pk;
}

// ---------------------------------------------------------------------------
extern "C" void kernel_launch(void* const* d_in, const int* in_sizes, int n_in,
                              void* d_out, int out_size, void* d_ws, size_t ws_size,
                              hipStream_t stream) {
    const float* x    = (const float*)d_in[0];
    const float* cosp = (const float*)d_in[1];
    const float* sinp = (const float*)d_in[2];
    const float* wq   = (const float*)d_in[3];
    const float* wk   = (const float*)d_in[4];
    const float* wv   = (const float*)d_in[5];
    const float* wo   = (const float*)d_in[6];
    float* out = (float*)d_out;

    const int Mrows = BATCH * SLEN;   // 4096

    // workspace layout (bf16 elems then fp32): xb/Ob alias (xb dead by then)
    short* xb = (short*)d_ws;                         // 4096*1024 bf16 (8 MB)
    short* Ob = xb;                                   // alias
    short* wT = xb + (size_t)Mrows * 1024;            // 2560*1024 bf16 (5 MB)
    short* Qb = wT + (size_t)2560 * 1024;             // 4096*1024 bf16 (8 MB)
    short* Kb = Qb + (size_t)Mrows * 1024;            // 4096*256  bf16 (2 MB)
    short* Vt = Kb + (size_t)Mrows * 256;             // 4096*256  bf16 (2 MB)
    short* Vb = Vt + (size_t)Mrows * 256;             // 4096*256  bf16 (2 MB)
    float* Op = (float*)(Vb + (size_t)Mrows * 256);   // NCH*4.19M fp32 (67 MB)
    float* Lp = Op + (size_t)NCH * PSTRIDE;           // NCH*65536 fp32 (1 MB)

    // fused: weight transposes + x->bf16
    prep_all<<<dim3(16, 48), 256, 0, stream>>>(wq, wk, wv, wo, wT, x, xb);

    // fused QKV projection + RoPE (V in natural layout). grid 12x64 = 768
    gemm_abt<0><<<dim3(1536 / 128, Mrows / 64), 256, 0, stream>>>(
        xb, wT, Mrows, 1536, DM, nullptr, Qb, Kb, Vb, cosp, sinp);

    // V transpose + key permutation (coalesced)
    vtrans_b<<<dim3(SLEN / 64, NKH, BATCH), 256, 0, stream>>>(Vb, Vt);

    // causal GQA flash attention, K-split into NCH chunks of 512 keys
    flash_mfma<<<dim3(SLEN / 32, NKH * NCH, BATCH), 256, 0, stream>>>(
        Qb, Kb, Vt, Ob, Op, Lp);

    // combine partials for s >= 512
    combine_k<<<(BATCH * 1536 * NH * 16) / 256, 256, 0, stream>>>(Op, Lp, Ob);

    // output projection (fp32 out). grid 8x64 = 512
    gemm_abt<1><<<dim3(DM / 128, Mrows / 64), 256, 0, stream>>>(
        Ob, wT + (size_t)1536 * 1024, Mrows, DM, DM, out,
        nullptr, nullptr, nullptr, nullptr, nullptr);
}